// Round 4
// baseline (770.267 us; speedup 1.0000x reference)
//
#include <hip/hip_runtime.h>

#define NN 50000
#define NE 600000
#define NG 512
#define HD 128
#define EPSV 1e-5f

__device__ inline void atomicAddF(float* p, float v) {
  __hip_atomic_fetch_add(p, v, __ATOMIC_RELAXED, __HIP_MEMORY_SCOPE_AGENT);
}

// ---- CSR build (with self-edge first in each node's list) ----
__global__ __launch_bounds__(256) void k_count(const int* __restrict__ dst, int* __restrict__ cnt) {
  int e = blockIdx.x * 256 + threadIdx.x;
  if (e < NE) atomicAdd(&cnt[dst[e]], 1);
}

// 4 elements per thread, 13 iterations
__global__ __launch_bounds__(1024) void k_scan(const int* __restrict__ cnt, int* __restrict__ off,
                                               int* __restrict__ cursor, float* __restrict__ dinv,
                                               int* __restrict__ csr) {
  __shared__ int part[16];
  __shared__ int partscan[16];
  int t = threadIdx.x;
  int lane = t & 63, w = t >> 6;
  int carry = 0;
  for (int base = 0; base < NN; base += 4096) {
    int i0 = base + 4 * t;
    int c[4], v[4];
#pragma unroll
    for (int j = 0; j < 4; j++) {
      int idx = i0 + j;
      c[j] = (idx < NN) ? cnt[idx] : 0;
      v[j] = (idx < NN) ? (c[j] + 1) : 0;
    }
    int tsum = (v[0] + v[1]) + (v[2] + v[3]);
    int val = tsum;
#pragma unroll
    for (int s = 1; s < 64; s <<= 1) {
      int u = __shfl_up(val, s);
      if (lane >= s) val += u;
    }
    if (lane == 63) part[w] = val;
    __syncthreads();
    if (t == 0) {
      int acc = 0;
#pragma unroll
      for (int i = 0; i < 16; i++) { acc += part[i]; partscan[i] = acc; }
    }
    __syncthreads();
    int waveoff = (w > 0) ? partscan[w - 1] : 0;
    int run = val - tsum + waveoff + carry;   // exclusive prefix for this thread's 4
#pragma unroll
    for (int j = 0; j < 4; j++) {
      int idx = i0 + j;
      if (idx < NN) {
        off[idx] = run;
        cursor[idx] = run + 1;
        csr[run] = idx;                        // self-edge
        dinv[idx] = rsqrtf((float)c[j] + 1.0f);
        run += v[j];
      }
    }
    carry += partscan[15];
    __syncthreads();
  }
  if (t == 0) off[NN] = carry;
}

__global__ __launch_bounds__(256) void k_fill(const int* __restrict__ src, const int* __restrict__ dst,
                                              int* __restrict__ cursor, int* __restrict__ csr) {
  int e = blockIdx.x * 256 + threadIdx.x;
  if (e < NE) {
    int p = atomicAdd(&cursor[dst[e]], 1);
    csr[p] = src[e];
  }
}

// ---- fused embedding tables: T = emb @ W1[rows] ----
__global__ __launch_bounds__(128) void k_tabs(const float* __restrict__ emb0, const float* __restrict__ emb1,
                                              const float* __restrict__ emb2, const float* __restrict__ emb5,
                                              const float* __restrict__ W1, float* __restrict__ tabs,
                                              float* __restrict__ row0) {
  int r = blockIdx.x, f = threadIdx.x;
  if (r == 470) { row0[f] = W1[f]; return; }
  const float* e;
  int wbase;
  if (r < 96)      { e = emb0 + r * 32;        wbase = 1;  }
  else if (r < 192){ e = emb1 + (r - 96) * 32; wbase = 33; }
  else if (r < 288){ e = emb2 + (r - 192) * 32; wbase = 65; }
  else             { e = emb5 + (r - 288) * 32; wbase = 97; }
  float acc = 0.f;
#pragma unroll 8
  for (int k = 0; k < 32; k++) acc += e[k] * W1[(wbase + k) * HD + f];
  tabs[r * HD + f] = acc;
}

// ---- layer-1: embed + axpy + pre-scale by dinv ----
__global__ __launch_bounds__(256) void k_embed(const float* __restrict__ x, const float* __restrict__ tabs,
                                               const float* __restrict__ row0, const float* __restrict__ dinv,
                                               float* __restrict__ A) {
  int n = blockIdx.x * 2 + (threadIdx.x >> 7);
  int f = threadIdx.x & 127;
  if (n >= NN) return;
  float poss = x[n * 5 + 0];
  int i0 = (int)x[n * 5 + 1];
  int i1 = (int)x[n * 5 + 2];
  int i2 = (int)x[n * 5 + 3];
  int i5 = (int)x[n * 5 + 4];
  float hw = poss * row0[f] + tabs[i0 * HD + f] + tabs[(96 + i1) * HD + f] +
             tabs[(192 + i2) * HD + f] + tabs[(288 + i5) * HD + f];
  A[n * HD + f] = hw * dinv[n];
}

// ---- aggregation: streaming segmented sum; SGPR indices + saddr gathers ----
// CSR list per node = [self, neighbors...]; B[n] = dinv[n]*sum(A[list]) + bias.
#define AGG_NPW 4
#define AGG_NPB (4 * AGG_NPW)
__global__ __launch_bounds__(256, 6) void k_agg(const float* __restrict__ A, const int* __restrict__ off,
                                                const int* __restrict__ csr, const float* __restrict__ dinv,
                                                const float* __restrict__ bias, float* __restrict__ B,
                                                float* __restrict__ stats) {
  const int t = threadIdx.x, lane = t & 63, wave = t >> 6;
  const float2* __restrict__ A2 = (const float2*)A;
  float2* __restrict__ B2 = (float2*)B;
  const float2 bias2 = ((const float2*)bias)[lane];
  float2 st1 = make_float2(0.f, 0.f), st2 = make_float2(0.f, 0.f);

  const int n0 = blockIdx.x * AGG_NPB + wave * AGG_NPW;
  int sv = 0; float dvv = 0.f;
  {
    int q = n0 + lane;
    if (lane <= AGG_NPW) sv = off[q > NN ? NN : q];
    if (lane < AGG_NPW && q < NN) dvv = dinv[q];
  }
  const int s0 = __shfl(sv, 0);
  const int T = __shfl(sv, AGG_NPW) - s0;
  const long b0 = s0;

  // preload up to 192 edge indices (expected T ~ 52 for 4 nodes)
  int ia = 0, ib = 0, ic = 0;
  if (lane < T)        ia = csr[b0 + lane];
  if (lane + 64 < T)   ib = csr[b0 + 64 + lane];
  if (lane + 128 < T)  ic = csr[b0 + 128 + lane];

  float2 acc = make_float2(0.f, 0.f);
  int cur = 0;
  int rel_next = __shfl(sv, 1) - s0;
  float2 va[8], vb[8];

  // fast path: branch-free batch of 8, indices via readlane -> SGPR, saddr loads
#define LOADB(arr, qq) { \
  if ((qq) + 8 <= T && (qq) + 8 <= 192) { \
    _Pragma("unroll") \
    for (int k = 0; k < 8; k++) { \
      int qk = (qq) + k; \
      int idx; \
      if (qk < 64)       idx = __builtin_amdgcn_readlane(ia, qk); \
      else if (qk < 128) idx = __builtin_amdgcn_readlane(ib, qk - 64); \
      else               idx = __builtin_amdgcn_readlane(ic, qk - 128); \
      const float2* nbp = (const float2*)((const char*)A + ((long)idx << 9)); \
      arr[k] = nbp[lane]; \
    } \
  } else { \
    _Pragma("unroll") \
    for (int k = 0; k < 8; k++) { \
      int qk = (qq) + k; \
      float2 vv = make_float2(0.f, 0.f); \
      if (qk < T) { \
        int idxs = csr[b0 + qk]; \
        vv = A2[(size_t)idxs * 64 + lane]; \
      } \
      arr[k] = vv; \
    } \
  } }

#define FLUSH() { \
  int nn = n0 + cur; \
  if (nn < NN) { \
    float dv = __shfl(dvv, cur); \
    float2 o; \
    o.x = fmaf(acc.x, dv, bias2.x); \
    o.y = fmaf(acc.y, dv, bias2.y); \
    B2[(size_t)nn * 64 + lane] = o; \
    st1.x += o.x; st1.y += o.y; \
    st2.x += o.x * o.x; st2.y += o.y * o.y; \
  } \
  cur++; acc.x = 0.f; acc.y = 0.f; }

#define PROC(arr, qq) { \
  _Pragma("unroll") \
  for (int k = 0; k < 8; k++) { \
    int qk = (qq) + k; \
    if (qk >= T) break; \
    while (qk >= rel_next) { FLUSH(); rel_next = __shfl(sv, cur + 1) - s0; } \
    acc.x += arr[k].x; acc.y += arr[k].y; \
  } }

  if (T > 0) {
    LOADB(va, 0);
    int q = 0;
    while (true) {
      if (q + 8 < T) LOADB(vb, q + 8);
      PROC(va, q);
      q += 8; if (q >= T) break;
      if (q + 8 < T) LOADB(va, q + 8);
      PROC(vb, q);
      q += 8; if (q >= T) break;
    }
  }
  while (cur < AGG_NPW) { FLUSH(); }

#undef LOADB
#undef FLUSH
#undef PROC

  // block-level BN-stat reduction
  __shared__ float2 red[256];
  red[t] = st1;
  __syncthreads();
  float2 t1;
  if (wave == 0) {
    t1.x = red[lane].x + red[lane + 64].x + red[lane + 128].x + red[lane + 192].x;
    t1.y = red[lane].y + red[lane + 64].y + red[lane + 128].y + red[lane + 192].y;
  }
  __syncthreads();
  red[t] = st2;
  __syncthreads();
  if (wave == 0) {
    float2 t2;
    t2.x = red[lane].x + red[lane + 64].x + red[lane + 128].x + red[lane + 192].x;
    t2.y = red[lane].y + red[lane + 64].y + red[lane + 128].y + red[lane + 192].y;
    atomicAddF(&stats[2 * lane + 0], t1.x);
    atomicAddF(&stats[2 * lane + 1], t1.y);
    atomicAddF(&stats[128 + 2 * lane + 0], t2.x);
    atomicAddF(&stats[128 + 2 * lane + 1], t2.y);
  }
}

// ---- BN finalize -> affine a,c ----
__global__ __launch_bounds__(128) void k_affine(const float* __restrict__ stats, const float* __restrict__ g,
                                                const float* __restrict__ be, float* __restrict__ af,
                                                float* __restrict__ cf) {
  int f = threadIdx.x;
  float mean = stats[f] * (1.f / NN);
  float var = stats[128 + f] * (1.f / NN) - mean * mean;
  var = fmaxf(var, 0.f);
  float inv = rsqrtf(var + EPSV);
  float a = g[f] * inv;
  af[f] = a;
  cf[f] = be[f] - mean * a;
}

// ---- GEMM: Aout[n,:] = dinv[n] * (relu(af*Bin[n,:]+cf) @ W) ----
#define GT_N 128
#define GT_KC 32
__global__ __launch_bounds__(256) void k_gemm(const float* __restrict__ Bin, const float* __restrict__ W,
                                              const float* __restrict__ af, const float* __restrict__ cf,
                                              const float* __restrict__ dinv, float* __restrict__ Aout) {
  __shared__ float hs[GT_KC * 132];
  __shared__ float ws[GT_KC * 132];
  const int t = threadIdx.x;
  const int base = blockIdx.x * GT_N;
  const int tx = t & 15, ty = t >> 4;
  float acc[8][8];
#pragma unroll
  for (int a = 0; a < 8; a++)
#pragma unroll
    for (int b = 0; b < 8; b++) acc[a][b] = 0.f;

  for (int k0 = 0; k0 < HD; k0 += GT_KC) {
    __syncthreads();
    {
      const float4* W4 = (const float4*)(W + k0 * HD);
#pragma unroll
      for (int i = t; i < 1024; i += 256) {
        int row = i >> 5, c4 = i & 31;
        float4 v = W4[i];
        *(float4*)&ws[row * 132 + c4 * 4] = v;
      }
    }
    {
#pragma unroll
      for (int i = t; i < 1024; i += 256) {
        int node = i >> 3, c4 = i & 7;
        int n = base + node;
        float4 v = make_float4(0.f, 0.f, 0.f, 0.f);
        if (n < NN) v = *(const float4*)&Bin[(size_t)n * HD + k0 + c4 * 4];
        int kk = c4 * 4;
        float r0 = fmaxf(fmaf(af[k0 + kk + 0], v.x, cf[k0 + kk + 0]), 0.f);
        float r1 = fmaxf(fmaf(af[k0 + kk + 1], v.y, cf[k0 + kk + 1]), 0.f);
        float r2 = fmaxf(fmaf(af[k0 + kk + 2], v.z, cf[k0 + kk + 2]), 0.f);
        float r3 = fmaxf(fmaf(af[k0 + kk + 3], v.w, cf[k0 + kk + 3]), 0.f);
        hs[(kk + 0) * 132 + node] = r0;
        hs[(kk + 1) * 132 + node] = r1;
        hs[(kk + 2) * 132 + node] = r2;
        hs[(kk + 3) * 132 + node] = r3;
      }
    }
    __syncthreads();
#pragma unroll
    for (int k = 0; k < GT_KC; k++) {
      float4 h0 = *(float4*)&hs[k * 132 + ty * 8];
      float4 h1 = *(float4*)&hs[k * 132 + ty * 8 + 4];
      float4 w0 = *(float4*)&ws[k * 132 + tx * 8];
      float4 w1 = *(float4*)&ws[k * 132 + tx * 8 + 4];
      float hh[8] = {h0.x, h0.y, h0.z, h0.w, h1.x, h1.y, h1.z, h1.w};
      float wv[8] = {w0.x, w0.y, w0.z, w0.w, w1.x, w1.y, w1.z, w1.w};
#pragma unroll
      for (int a = 0; a < 8; a++)
#pragma unroll
        for (int b = 0; b < 8; b++) acc[a][b] = fmaf(hh[a], wv[b], acc[a][b]);
    }
  }
#pragma unroll
  for (int a = 0; a < 8; a++) {
    int n = base + ty * 8 + a;
    if (n < NN) {
      float s = dinv[n];
      float4 o0 = make_float4(acc[a][0] * s, acc[a][1] * s, acc[a][2] * s, acc[a][3] * s);
      float4 o1 = make_float4(acc[a][4] * s, acc[a][5] * s, acc[a][6] * s, acc[a][7] * s);
      *(float4*)&Aout[(size_t)n * HD + tx * 8] = o0;
      *(float4*)&Aout[(size_t)n * HD + tx * 8 + 4] = o1;
    }
  }
}

// ---- graph boundaries via binary search on sorted batch ----
__global__ __launch_bounds__(128) void k_bsearch(const int* __restrict__ batch, int* __restrict__ gstart) {
  int g = blockIdx.x * 128 + threadIdx.x;
  if (g > NG) return;
  if (g == NG) { gstart[NG] = NN; return; }
  int lo = 0, hi = NN;
  while (lo < hi) {
    int mid = (lo + hi) >> 1;
    if (batch[mid] < g) lo = mid + 1;
    else hi = mid;
  }
  gstart[g] = lo;
}

// ---- pool + FC ----
__global__ __launch_bounds__(128) void k_pool(const float* __restrict__ B, const float* __restrict__ af,
                                              const float* __restrict__ cf, const int* __restrict__ gstart,
                                              const float* __restrict__ fcW, const float* __restrict__ fcb,
                                              float* __restrict__ out) {
  int g = blockIdx.x, f = threadIdx.x;
  int gs = gstart[g], ge = gstart[g + 1];
  float a = af[f], c = cf[f];
  float a0 = 0.f, a1 = 0.f, a2 = 0.f, a3 = 0.f;
  int n = gs;
  for (; n + 4 <= ge; n += 4) {
    a0 += fmaxf(fmaf(a, B[(size_t)(n + 0) * HD + f], c), 0.f);
    a1 += fmaxf(fmaf(a, B[(size_t)(n + 1) * HD + f], c), 0.f);
    a2 += fmaxf(fmaf(a, B[(size_t)(n + 2) * HD + f], c), 0.f);
    a3 += fmaxf(fmaf(a, B[(size_t)(n + 3) * HD + f], c), 0.f);
  }
  for (; n < ge; n++) a0 += fmaxf(fmaf(a, B[(size_t)n * HD + f], c), 0.f);
  float acc = (a0 + a1) + (a2 + a3);
  float cntf = (float)(ge - gs);
  float pooled = acc / fmaxf(cntf, 1.f);
  __shared__ float lp[128];
  lp[f] = pooled;
  __syncthreads();
  if (f < 3) {
    float o = fcb[f];
    for (int k = 0; k < 128; k++) o += lp[k] * fcW[k * 3 + f];
    out[g * 3 + f] = o;
  }
}

extern "C" void kernel_launch(void* const* d_in, const int* in_sizes, int n_in,
                              void* d_out, int out_size, void* d_ws, size_t ws_size,
                              hipStream_t stream) {
  const float* x    = (const float*)d_in[0];
  const int* ei     = (const int*)d_in[1];
  const int* batch  = (const int*)d_in[2];
  const float* emb0 = (const float*)d_in[3];
  const float* emb1 = (const float*)d_in[4];
  const float* emb2 = (const float*)d_in[5];
  const float* emb5 = (const float*)d_in[6];
  const float* W1   = (const float*)d_in[7];
  const float* b1   = (const float*)d_in[8];
  const float* W2   = (const float*)d_in[9];
  const float* b2   = (const float*)d_in[10];
  const float* W3   = (const float*)d_in[11];
  const float* b3   = (const float*)d_in[12];
  const float* g1   = (const float*)d_in[13];
  const float* be1  = (const float*)d_in[14];
  const float* g2   = (const float*)d_in[15];
  const float* be2  = (const float*)d_in[16];
  const float* g3   = (const float*)d_in[17];
  const float* be3  = (const float*)d_in[18];
  const float* fcW  = (const float*)d_in[19];
  const float* fcb  = (const float*)d_in[20];
  float* out = (float*)d_out;

  const int* esrc = ei;
  const int* edst = ei + NE;

  char* p = (char*)d_ws;
  size_t o = 0;
  auto alloc = [&](size_t bytes) -> void* {
    o = (o + 255) & ~(size_t)255;
    void* r = p + o;
    o += bytes;
    return r;
  };
  int* cnt      = (int*)alloc(NN * 4);
  float* stats  = (float*)alloc(3 * 256 * 4);   // 3 layers x (sum,sumsq)
  size_t zbytes = o;                            // memset range covers cnt+stats
  int* off      = (int*)alloc((NN + 1) * 4);
  int* cursor   = (int*)alloc(NN * 4);
  int* csr      = (int*)alloc((size_t)(NE + NN) * 4);
  float* dinv   = (float*)alloc(NN * 4);
  float* tabs   = (float*)alloc(470 * HD * 4);
  float* row0   = (float*)alloc(HD * 4);
  float* affine = (float*)alloc(3 * 256 * 4);   // 3 layers x (a,c)
  int* gstart   = (int*)alloc((NG + 1) * 4);
  float* bufA   = (float*)alloc((size_t)NN * HD * 4);
  float* bufB   = (float*)alloc((size_t)NN * HD * 4);
  (void)ws_size; (void)n_in; (void)in_sizes; (void)out_size;

  hipMemsetAsync(d_ws, 0, zbytes, stream);

  k_count<<<(NE + 255) / 256, 256, 0, stream>>>(edst, cnt);
  k_scan<<<1, 1024, 0, stream>>>(cnt, off, cursor, dinv, csr);
  k_fill<<<(NE + 255) / 256, 256, 0, stream>>>(esrc, edst, cursor, csr);
  k_tabs<<<471, 128, 0, stream>>>(emb0, emb1, emb2, emb5, W1, tabs, row0);
  k_bsearch<<<5, 128, 0, stream>>>(batch, gstart);
  k_embed<<<NN / 2, 256, 0, stream>>>(x, tabs, row0, dinv, bufA);

  const int nagg = (NN + AGG_NPB - 1) / AGG_NPB;
  const int ngemm = (NN + GT_N - 1) / GT_N;

  // layer 1
  k_agg<<<nagg, 256, 0, stream>>>(bufA, off, csr, dinv, b1, bufB, stats + 0);
  k_affine<<<1, 128, 0, stream>>>(stats + 0, g1, be1, affine + 0, affine + 128);
  // layer 2
  k_gemm<<<ngemm, 256, 0, stream>>>(bufB, W2, affine + 0, affine + 128, dinv, bufA);
  k_agg<<<nagg, 256, 0, stream>>>(bufA, off, csr, dinv, b2, bufB, stats + 256);
  k_affine<<<1, 128, 0, stream>>>(stats + 256, g2, be2, affine + 256, affine + 384);
  // layer 3
  k_gemm<<<ngemm, 256, 0, stream>>>(bufB, W3, affine + 256, affine + 384, dinv, bufA);
  k_agg<<<nagg, 256, 0, stream>>>(bufA, off, csr, dinv, b3, bufB, stats + 512);
  k_affine<<<1, 128, 0, stream>>>(stats + 512, g3, be3, affine + 512, affine + 640);
  // pool + fc
  k_pool<<<NG, 128, 0, stream>>>(bufB, affine + 512, affine + 640, gstart, fcW, fcb, out);
}

// Round 5
// 752.123 us; speedup vs baseline: 1.0241x; 1.0241x over previous
//
#include <hip/hip_runtime.h>

#define NN 50000
#define NE 600000
#define NG 512
#define HD 128
#define EPSV 1e-5f

__device__ inline void atomicAddF(float* p, float v) {
  __hip_atomic_fetch_add(p, v, __ATOMIC_RELAXED, __HIP_MEMORY_SCOPE_AGENT);
}

// ---- CSR build (self-edge first in each node's list) ----
__global__ __launch_bounds__(256) void k_count(const int* __restrict__ dst, int* __restrict__ cnt) {
  int e = blockIdx.x * 256 + threadIdx.x;
  if (e < NE) atomicAdd(&cnt[dst[e]], 1);
}

// 4 elements per thread, 13 iterations; also zeroes bufA's pad row NN.
__global__ __launch_bounds__(1024) void k_scan(const int* __restrict__ cnt, int* __restrict__ off,
                                               int* __restrict__ cursor, float* __restrict__ dinv,
                                               int* __restrict__ csr, float* __restrict__ zrowA) {
  __shared__ int part[16];
  __shared__ int partscan[16];
  int t = threadIdx.x;
  int lane = t & 63, w = t >> 6;
  if (t < HD) zrowA[t] = 0.f;   // zero pad row (gather target for padding)
  int carry = 0;
  for (int base = 0; base < NN; base += 4096) {
    int i0 = base + 4 * t;
    int c[4], v[4];
#pragma unroll
    for (int j = 0; j < 4; j++) {
      int idx = i0 + j;
      c[j] = (idx < NN) ? cnt[idx] : 0;
      v[j] = (idx < NN) ? (c[j] + 1) : 0;
    }
    int tsum = (v[0] + v[1]) + (v[2] + v[3]);
    int val = tsum;
#pragma unroll
    for (int s = 1; s < 64; s <<= 1) {
      int u = __shfl_up(val, s);
      if (lane >= s) val += u;
    }
    if (lane == 63) part[w] = val;
    __syncthreads();
    if (t == 0) {
      int acc = 0;
#pragma unroll
      for (int i = 0; i < 16; i++) { acc += part[i]; partscan[i] = acc; }
    }
    __syncthreads();
    int waveoff = (w > 0) ? partscan[w - 1] : 0;
    int run = val - tsum + waveoff + carry;
#pragma unroll
    for (int j = 0; j < 4; j++) {
      int idx = i0 + j;
      if (idx < NN) {
        off[idx] = run;
        cursor[idx] = run + 1;
        csr[run] = idx;                        // self-edge
        dinv[idx] = rsqrtf((float)c[j] + 1.0f);
        run += v[j];
      }
    }
    carry += partscan[15];
    __syncthreads();
  }
  if (t == 0) off[NN] = carry;
}

__global__ __launch_bounds__(256) void k_fill(const int* __restrict__ src, const int* __restrict__ dst,
                                              int* __restrict__ cursor, int* __restrict__ csr) {
  int e = blockIdx.x * 256 + threadIdx.x;
  if (e < NE) {
    int p = atomicAdd(&cursor[dst[e]], 1);
    csr[p] = src[e];
  }
}

// ---- fused embedding tables: T = emb @ W1[rows] ----
__global__ __launch_bounds__(128) void k_tabs(const float* __restrict__ emb0, const float* __restrict__ emb1,
                                              const float* __restrict__ emb2, const float* __restrict__ emb5,
                                              const float* __restrict__ W1, float* __restrict__ tabs,
                                              float* __restrict__ row0) {
  int r = blockIdx.x, f = threadIdx.x;
  if (r == 470) { row0[f] = W1[f]; return; }
  const float* e;
  int wbase;
  if (r < 96)      { e = emb0 + r * 32;        wbase = 1;  }
  else if (r < 192){ e = emb1 + (r - 96) * 32; wbase = 33; }
  else if (r < 288){ e = emb2 + (r - 192) * 32; wbase = 65; }
  else             { e = emb5 + (r - 288) * 32; wbase = 97; }
  float acc = 0.f;
#pragma unroll 8
  for (int k = 0; k < 32; k++) acc += e[k] * W1[(wbase + k) * HD + f];
  tabs[r * HD + f] = acc;
}

// ---- layer-1: embed + axpy + pre-scale by dinv ----
__global__ __launch_bounds__(256) void k_embed(const float* __restrict__ x, const float* __restrict__ tabs,
                                               const float* __restrict__ row0, const float* __restrict__ dinv,
                                               float* __restrict__ A) {
  int n = blockIdx.x * 2 + (threadIdx.x >> 7);
  int f = threadIdx.x & 127;
  if (n >= NN) return;
  float poss = x[n * 5 + 0];
  int i0 = (int)x[n * 5 + 1];
  int i1 = (int)x[n * 5 + 2];
  int i2 = (int)x[n * 5 + 3];
  int i5 = (int)x[n * 5 + 4];
  float hw = poss * row0[f] + tabs[i0 * HD + f] + tabs[(96 + i1) * HD + f] +
             tabs[(192 + i2) * HD + f] + tabs[(288 + i5) * HD + f];
  A[n * HD + f] = hw * dinv[n];
}

// ---- aggregation v5: node-per-wave-step, branch-free unroll-16 gather clause.
// CSR list per node = [self, neighbors...]; B[n] = dinv[n]*sum(A[list]) + bias.
// Padding loads read zeroed row NN of A. Wave-uniform n -> s_load meta,
// readlane -> SGPR base gathers with shared lane*8 voffset.
#define AGG_NPW 4
#define AGG_NPB (4 * AGG_NPW)
__global__ __launch_bounds__(256) void k_agg(const float* __restrict__ A, const int* __restrict__ off,
                                             const int* __restrict__ csr, const float* __restrict__ dinv,
                                             const float* __restrict__ bias, float* __restrict__ B,
                                             float* __restrict__ stats) {
  const int t = threadIdx.x, lane = t & 63, wave = t >> 6;
  const float2* __restrict__ A2 = (const float2*)A;
  float2* __restrict__ B2 = (float2*)B;
  const float2 bias2 = ((const float2*)bias)[lane];
  float2 st1 = make_float2(0.f, 0.f), st2 = make_float2(0.f, 0.f);

  const int n0 = blockIdx.x * AGG_NPB + wave * AGG_NPW;  // grid exact: n0+3 < NN
#pragma unroll 1
  for (int i = 0; i < AGG_NPW; i++) {
    const int n = n0 + i;
    const int ks = off[n];
    const int ke = off[n + 1];
    const int deg = ke - ks;                 // >= 1 (self)
    float2 acc = make_float2(0.f, 0.f);
#pragma unroll 1
    for (int c0 = 0; c0 < deg; c0 += 64) {
      const int rem = deg - c0;
      const int ev = (lane < rem) ? csr[ks + c0 + lane] : NN;
      const int lim = rem < 64 ? rem : 64;
#pragma unroll 1
      for (int k0 = 0; k0 < lim; k0 += 16) {
        float2 v[16];
#pragma unroll
        for (int k = 0; k < 16; k++) {
          int sidx = __builtin_amdgcn_readlane(ev, k0 + k);  // pad lanes give NN
          v[k] = A2[(size_t)sidx * 64 + lane];
        }
        float2 s0 = make_float2(0.f, 0.f), s1 = make_float2(0.f, 0.f);
        float2 s2 = make_float2(0.f, 0.f), s3 = make_float2(0.f, 0.f);
#pragma unroll
        for (int k = 0; k < 16; k += 4) {
          s0.x += v[k].x;     s0.y += v[k].y;
          s1.x += v[k + 1].x; s1.y += v[k + 1].y;
          s2.x += v[k + 2].x; s2.y += v[k + 2].y;
          s3.x += v[k + 3].x; s3.y += v[k + 3].y;
        }
        acc.x += (s0.x + s1.x) + (s2.x + s3.x);
        acc.y += (s0.y + s1.y) + (s2.y + s3.y);
      }
    }
    const float dv = dinv[n];
    float2 o;
    o.x = fmaf(acc.x, dv, bias2.x);
    o.y = fmaf(acc.y, dv, bias2.y);
    B2[(size_t)n * 64 + lane] = o;
    st1.x += o.x; st1.y += o.y;
    st2.x += o.x * o.x; st2.y += o.y * o.y;
  }

  // block-level BN-stat reduction (4 waves cover the same 128 features)
  __shared__ float2 red[256];
  red[t] = st1;
  __syncthreads();
  float2 t1;
  if (wave == 0) {
    t1.x = red[lane].x + red[lane + 64].x + red[lane + 128].x + red[lane + 192].x;
    t1.y = red[lane].y + red[lane + 64].y + red[lane + 128].y + red[lane + 192].y;
  }
  __syncthreads();
  red[t] = st2;
  __syncthreads();
  if (wave == 0) {
    float2 t2;
    t2.x = red[lane].x + red[lane + 64].x + red[lane + 128].x + red[lane + 192].x;
    t2.y = red[lane].y + red[lane + 64].y + red[lane + 128].y + red[lane + 192].y;
    atomicAddF(&stats[2 * lane + 0], t1.x);
    atomicAddF(&stats[2 * lane + 1], t1.y);
    atomicAddF(&stats[128 + 2 * lane + 0], t2.x);
    atomicAddF(&stats[128 + 2 * lane + 1], t2.y);
  }
}

// ---- BN finalize -> affine a,c ----
__global__ __launch_bounds__(128) void k_affine(const float* __restrict__ stats, const float* __restrict__ g,
                                                const float* __restrict__ be, float* __restrict__ af,
                                                float* __restrict__ cf) {
  int f = threadIdx.x;
  float mean = stats[f] * (1.f / NN);
  float var = stats[128 + f] * (1.f / NN) - mean * mean;
  var = fmaxf(var, 0.f);
  float inv = rsqrtf(var + EPSV);
  float a = g[f] * inv;
  af[f] = a;
  cf[f] = be[f] - mean * a;
}

// ---- GEMM: Aout[n,:] = dinv[n] * (relu(af*Bin[n,:]+cf) @ W) ----
#define GT_N 128
#define GT_KC 32
__global__ __launch_bounds__(256) void k_gemm(const float* __restrict__ Bin, const float* __restrict__ W,
                                              const float* __restrict__ af, const float* __restrict__ cf,
                                              const float* __restrict__ dinv, float* __restrict__ Aout) {
  __shared__ float hs[GT_KC * 132];
  __shared__ float ws[GT_KC * 132];
  const int t = threadIdx.x;
  const int base = blockIdx.x * GT_N;
  const int tx = t & 15, ty = t >> 4;
  float acc[8][8];
#pragma unroll
  for (int a = 0; a < 8; a++)
#pragma unroll
    for (int b = 0; b < 8; b++) acc[a][b] = 0.f;

  for (int k0 = 0; k0 < HD; k0 += GT_KC) {
    __syncthreads();
    {
      const float4* W4 = (const float4*)(W + k0 * HD);
#pragma unroll
      for (int i = t; i < 1024; i += 256) {
        int row = i >> 5, c4 = i & 31;
        float4 v = W4[i];
        *(float4*)&ws[row * 132 + c4 * 4] = v;
      }
    }
    {
#pragma unroll
      for (int i = t; i < 1024; i += 256) {
        int node = i >> 3, c4 = i & 7;
        int n = base + node;
        float4 v = make_float4(0.f, 0.f, 0.f, 0.f);
        if (n < NN) v = *(const float4*)&Bin[(size_t)n * HD + k0 + c4 * 4];
        int kk = c4 * 4;
        float r0 = fmaxf(fmaf(af[k0 + kk + 0], v.x, cf[k0 + kk + 0]), 0.f);
        float r1 = fmaxf(fmaf(af[k0 + kk + 1], v.y, cf[k0 + kk + 1]), 0.f);
        float r2 = fmaxf(fmaf(af[k0 + kk + 2], v.z, cf[k0 + kk + 2]), 0.f);
        float r3 = fmaxf(fmaf(af[k0 + kk + 3], v.w, cf[k0 + kk + 3]), 0.f);
        hs[(kk + 0) * 132 + node] = r0;
        hs[(kk + 1) * 132 + node] = r1;
        hs[(kk + 2) * 132 + node] = r2;
        hs[(kk + 3) * 132 + node] = r3;
      }
    }
    __syncthreads();
#pragma unroll
    for (int k = 0; k < GT_KC; k++) {
      float4 h0 = *(float4*)&hs[k * 132 + ty * 8];
      float4 h1 = *(float4*)&hs[k * 132 + ty * 8 + 4];
      float4 w0 = *(float4*)&ws[k * 132 + tx * 8];
      float4 w1 = *(float4*)&ws[k * 132 + tx * 8 + 4];
      float hh[8] = {h0.x, h0.y, h0.z, h0.w, h1.x, h1.y, h1.z, h1.w};
      float wv[8] = {w0.x, w0.y, w0.z, w0.w, w1.x, w1.y, w1.z, w1.w};
#pragma unroll
      for (int a = 0; a < 8; a++)
#pragma unroll
        for (int b = 0; b < 8; b++) acc[a][b] = fmaf(hh[a], wv[b], acc[a][b]);
    }
  }
#pragma unroll
  for (int a = 0; a < 8; a++) {
    int n = base + ty * 8 + a;
    if (n < NN) {
      float s = dinv[n];
      float4 o0 = make_float4(acc[a][0] * s, acc[a][1] * s, acc[a][2] * s, acc[a][3] * s);
      float4 o1 = make_float4(acc[a][4] * s, acc[a][5] * s, acc[a][6] * s, acc[a][7] * s);
      *(float4*)&Aout[(size_t)n * HD + tx * 8] = o0;
      *(float4*)&Aout[(size_t)n * HD + tx * 8 + 4] = o1;
    }
  }
}

// ---- graph boundaries via binary search on sorted batch ----
__global__ __launch_bounds__(128) void k_bsearch(const int* __restrict__ batch, int* __restrict__ gstart) {
  int g = blockIdx.x * 128 + threadIdx.x;
  if (g > NG) return;
  if (g == NG) { gstart[NG] = NN; return; }
  int lo = 0, hi = NN;
  while (lo < hi) {
    int mid = (lo + hi) >> 1;
    if (batch[mid] < g) lo = mid + 1;
    else hi = mid;
  }
  gstart[g] = lo;
}

// ---- pool + FC ----
__global__ __launch_bounds__(128) void k_pool(const float* __restrict__ B, const float* __restrict__ af,
                                              const float* __restrict__ cf, const int* __restrict__ gstart,
                                              const float* __restrict__ fcW, const float* __restrict__ fcb,
                                              float* __restrict__ out) {
  int g = blockIdx.x, f = threadIdx.x;
  int gs = gstart[g], ge = gstart[g + 1];
  float a = af[f], c = cf[f];
  float a0 = 0.f, a1 = 0.f, a2 = 0.f, a3 = 0.f;
  int n = gs;
  for (; n + 4 <= ge; n += 4) {
    a0 += fmaxf(fmaf(a, B[(size_t)(n + 0) * HD + f], c), 0.f);
    a1 += fmaxf(fmaf(a, B[(size_t)(n + 1) * HD + f], c), 0.f);
    a2 += fmaxf(fmaf(a, B[(size_t)(n + 2) * HD + f], c), 0.f);
    a3 += fmaxf(fmaf(a, B[(size_t)(n + 3) * HD + f], c), 0.f);
  }
  for (; n < ge; n++) a0 += fmaxf(fmaf(a, B[(size_t)n * HD + f], c), 0.f);
  float acc = (a0 + a1) + (a2 + a3);
  float cntf = (float)(ge - gs);
  float pooled = acc / fmaxf(cntf, 1.f);
  __shared__ float lp[128];
  lp[f] = pooled;
  __syncthreads();
  if (f < 3) {
    float o = fcb[f];
    for (int k = 0; k < 128; k++) o += lp[k] * fcW[k * 3 + f];
    out[g * 3 + f] = o;
  }
}

extern "C" void kernel_launch(void* const* d_in, const int* in_sizes, int n_in,
                              void* d_out, int out_size, void* d_ws, size_t ws_size,
                              hipStream_t stream) {
  const float* x    = (const float*)d_in[0];
  const int* ei     = (const int*)d_in[1];
  const int* batch  = (const int*)d_in[2];
  const float* emb0 = (const float*)d_in[3];
  const float* emb1 = (const float*)d_in[4];
  const float* emb2 = (const float*)d_in[5];
  const float* emb5 = (const float*)d_in[6];
  const float* W1   = (const float*)d_in[7];
  const float* b1   = (const float*)d_in[8];
  const float* W2   = (const float*)d_in[9];
  const float* b2   = (const float*)d_in[10];
  const float* W3   = (const float*)d_in[11];
  const float* b3   = (const float*)d_in[12];
  const float* g1   = (const float*)d_in[13];
  const float* be1  = (const float*)d_in[14];
  const float* g2   = (const float*)d_in[15];
  const float* be2  = (const float*)d_in[16];
  const float* g3   = (const float*)d_in[17];
  const float* be3  = (const float*)d_in[18];
  const float* fcW  = (const float*)d_in[19];
  const float* fcb  = (const float*)d_in[20];
  float* out = (float*)d_out;

  const int* esrc = ei;
  const int* edst = ei + NE;

  char* p = (char*)d_ws;
  size_t o = 0;
  auto alloc = [&](size_t bytes) -> void* {
    o = (o + 255) & ~(size_t)255;
    void* r = p + o;
    o += bytes;
    return r;
  };
  int* cnt      = (int*)alloc(NN * 4);
  float* stats  = (float*)alloc(3 * 256 * 4);   // 3 layers x (sum,sumsq)
  size_t zbytes = o;                            // memset range covers cnt+stats
  int* off      = (int*)alloc((NN + 1) * 4);
  int* cursor   = (int*)alloc(NN * 4);
  int* csr      = (int*)alloc((size_t)(NE + NN + 64) * 4);
  float* dinv   = (float*)alloc(NN * 4);
  float* tabs   = (float*)alloc(470 * HD * 4);
  float* row0   = (float*)alloc(HD * 4);
  float* affine = (float*)alloc(3 * 256 * 4);   // 3 layers x (a,c)
  int* gstart   = (int*)alloc((NG + 1) * 4);
  float* bufA   = (float*)alloc((size_t)(NN + 1) * HD * 4);  // +1 zero pad row
  float* bufB   = (float*)alloc((size_t)(NN + 1) * HD * 4);
  (void)ws_size; (void)n_in; (void)in_sizes; (void)out_size;

  hipMemsetAsync(d_ws, 0, zbytes, stream);

  k_count<<<(NE + 255) / 256, 256, 0, stream>>>(edst, cnt);
  k_scan<<<1, 1024, 0, stream>>>(cnt, off, cursor, dinv, csr, bufA + (size_t)NN * HD);
  k_fill<<<(NE + 255) / 256, 256, 0, stream>>>(esrc, edst, cursor, csr);
  k_tabs<<<471, 128, 0, stream>>>(emb0, emb1, emb2, emb5, W1, tabs, row0);
  k_bsearch<<<5, 128, 0, stream>>>(batch, gstart);
  k_embed<<<NN / 2, 256, 0, stream>>>(x, tabs, row0, dinv, bufA);

  const int nagg = NN / AGG_NPB;            // 3125, exact
  const int ngemm = (NN + GT_N - 1) / GT_N;

  // layer 1
  k_agg<<<nagg, 256, 0, stream>>>(bufA, off, csr, dinv, b1, bufB, stats + 0);
  k_affine<<<1, 128, 0, stream>>>(stats + 0, g1, be1, affine + 0, affine + 128);
  // layer 2
  k_gemm<<<ngemm, 256, 0, stream>>>(bufB, W2, affine + 0, affine + 128, dinv, bufA);
  k_agg<<<nagg, 256, 0, stream>>>(bufA, off, csr, dinv, b2, bufB, stats + 256);
  k_affine<<<1, 128, 0, stream>>>(stats + 256, g2, be2, affine + 256, affine + 384);
  // layer 3
  k_gemm<<<ngemm, 256, 0, stream>>>(bufB, W3, affine + 256, affine + 384, dinv, bufA);
  k_agg<<<nagg, 256, 0, stream>>>(bufA, off, csr, dinv, b3, bufB, stats + 512);
  k_affine<<<1, 128, 0, stream>>>(stats + 512, g3, be3, affine + 512, affine + 640);
  // pool + fc
  k_pool<<<NG, 128, 0, stream>>>(bufB, affine + 512, affine + 640, gstart, fcW, fcb, out);
}

// Round 6
// 744.893 us; speedup vs baseline: 1.0341x; 1.0097x over previous
//
#include <hip/hip_runtime.h>

#define NN 50000
#define NE 600000
#define NG 512
#define HD 128
#define EPSV 1e-5f

typedef unsigned int uint;

__device__ inline void atomicAddF(float* p, float v) {
  __hip_atomic_fetch_add(p, v, __ATOMIC_RELAXED, __HIP_MEMORY_SCOPE_AGENT);
}

__device__ inline uint bf16rne(float f) {
  uint u = __float_as_uint(f);
  return (u + 0x7fffu + ((u >> 16) & 1u)) >> 16;
}
__device__ inline uint pack2bf(float a, float b) {
  return bf16rne(a) | (bf16rne(b) << 16);
}

// ---- CSR build (self-edge first in each node's list) ----
__global__ __launch_bounds__(256) void k_count(const int* __restrict__ dst, int* __restrict__ cnt) {
  int e = blockIdx.x * 256 + threadIdx.x;
  if (e < NE) atomicAdd(&cnt[dst[e]], 1);
}

// 4 elements per thread, 13 iterations; also zeroes Abf's pad row NN.
__global__ __launch_bounds__(1024) void k_scan(const int* __restrict__ cnt, int* __restrict__ off,
                                               int* __restrict__ cursor, float* __restrict__ dinv,
                                               int* __restrict__ csr, uint* __restrict__ zrow) {
  __shared__ int part[16];
  __shared__ int partscan[16];
  int t = threadIdx.x;
  int lane = t & 63, w = t >> 6;
  if (t < 64) zrow[t] = 0u;   // zero pad row (bf16 row = 64 uints)
  int carry = 0;
  for (int base = 0; base < NN; base += 4096) {
    int i0 = base + 4 * t;
    int c[4], v[4];
#pragma unroll
    for (int j = 0; j < 4; j++) {
      int idx = i0 + j;
      c[j] = (idx < NN) ? cnt[idx] : 0;
      v[j] = (idx < NN) ? (c[j] + 1) : 0;
    }
    int tsum = (v[0] + v[1]) + (v[2] + v[3]);
    int val = tsum;
#pragma unroll
    for (int s = 1; s < 64; s <<= 1) {
      int u = __shfl_up(val, s);
      if (lane >= s) val += u;
    }
    if (lane == 63) part[w] = val;
    __syncthreads();
    if (t == 0) {
      int acc = 0;
#pragma unroll
      for (int i = 0; i < 16; i++) { acc += part[i]; partscan[i] = acc; }
    }
    __syncthreads();
    int waveoff = (w > 0) ? partscan[w - 1] : 0;
    int run = val - tsum + waveoff + carry;
#pragma unroll
    for (int j = 0; j < 4; j++) {
      int idx = i0 + j;
      if (idx < NN) {
        off[idx] = run;
        cursor[idx] = run + 1;
        csr[run] = idx;                        // self-edge
        dinv[idx] = rsqrtf((float)c[j] + 1.0f);
        run += v[j];
      }
    }
    carry += partscan[15];
    __syncthreads();
  }
  if (t == 0) off[NN] = carry;
}

__global__ __launch_bounds__(256) void k_fill(const int* __restrict__ src, const int* __restrict__ dst,
                                              int* __restrict__ cursor, int* __restrict__ csr) {
  int e = blockIdx.x * 256 + threadIdx.x;
  if (e < NE) {
    int p = atomicAdd(&cursor[dst[e]], 1);
    csr[p] = src[e];
  }
}

// ---- fused embedding tables: T = emb @ W1[rows] ----
__global__ __launch_bounds__(128) void k_tabs(const float* __restrict__ emb0, const float* __restrict__ emb1,
                                              const float* __restrict__ emb2, const float* __restrict__ emb5,
                                              const float* __restrict__ W1, float* __restrict__ tabs,
                                              float* __restrict__ row0) {
  int r = blockIdx.x, f = threadIdx.x;
  if (r == 470) { row0[f] = W1[f]; return; }
  const float* e;
  int wbase;
  if (r < 96)      { e = emb0 + r * 32;        wbase = 1;  }
  else if (r < 192){ e = emb1 + (r - 96) * 32; wbase = 33; }
  else if (r < 288){ e = emb2 + (r - 192) * 32; wbase = 65; }
  else             { e = emb5 + (r - 288) * 32; wbase = 97; }
  float acc = 0.f;
#pragma unroll 8
  for (int k = 0; k < 32; k++) acc += e[k] * W1[(wbase + k) * HD + f];
  tabs[r * HD + f] = acc;
}

// ---- layer-1: embed + axpy + pre-scale by dinv; packed bf16 output ----
__global__ __launch_bounds__(256) void k_embed(const float* __restrict__ x, const float2* __restrict__ tabs2,
                                               const float2* __restrict__ row02, const float* __restrict__ dinv,
                                               uint* __restrict__ Abf) {
  int n = blockIdx.x * 4 + (threadIdx.x >> 6);   // grid exact: 12500*4 = NN
  int lane = threadIdx.x & 63;
  float poss = x[n * 5 + 0];
  int i0 = (int)x[n * 5 + 1];
  int i1 = (int)x[n * 5 + 2];
  int i2 = (int)x[n * 5 + 3];
  int i5 = (int)x[n * 5 + 4];
  float2 r0 = row02[lane];
  float2 t0 = tabs2[(size_t)i0 * 64 + lane];
  float2 t1 = tabs2[(size_t)(96 + i1) * 64 + lane];
  float2 t2 = tabs2[(size_t)(192 + i2) * 64 + lane];
  float2 t5 = tabs2[(size_t)(288 + i5) * 64 + lane];
  float hx = poss * r0.x + t0.x + t1.x + t2.x + t5.x;
  float hy = poss * r0.y + t0.y + t1.y + t2.y + t5.y;
  float dv = dinv[n];
  Abf[(size_t)n * 64 + lane] = pack2bf(hx * dv, hy * dv);
}

// ---- aggregation: node-per-wave-step, branch-free unroll-16 bf16 gather clause.
// CSR list per node = [self, neighbors...]; B[n] = dinv[n]*sum(Abf[list]) + bias.
// Padding loads read zeroed row NN of Abf.
#define AGG_NPW 4
#define AGG_NPB (4 * AGG_NPW)
__global__ __launch_bounds__(256) void k_agg(const uint* __restrict__ Abf, const int* __restrict__ off,
                                             const int* __restrict__ csr, const float* __restrict__ dinv,
                                             const float* __restrict__ bias, float* __restrict__ B,
                                             float* __restrict__ stats) {
  const int t = threadIdx.x, lane = t & 63, wave = t >> 6;
  float2* __restrict__ B2 = (float2*)B;
  const float2 bias2 = ((const float2*)bias)[lane];
  float2 st1 = make_float2(0.f, 0.f), st2 = make_float2(0.f, 0.f);

  const int n0 = blockIdx.x * AGG_NPB + wave * AGG_NPW;  // grid exact
#pragma unroll 1
  for (int i = 0; i < AGG_NPW; i++) {
    const int n = n0 + i;
    const int ks = off[n];
    const int ke = off[n + 1];
    const int deg = ke - ks;                 // >= 1 (self)
    float accx = 0.f, accy = 0.f;
#pragma unroll 1
    for (int c0 = 0; c0 < deg; c0 += 64) {
      const int rem = deg - c0;
      const int ev = (lane < rem) ? csr[ks + c0 + lane] : NN;
      const int lim = rem < 64 ? rem : 64;
#pragma unroll 1
      for (int k0 = 0; k0 < lim; k0 += 16) {
        uint v[16];
#pragma unroll
        for (int k = 0; k < 16; k++) {
          int sidx = __builtin_amdgcn_readlane(ev, k0 + k);  // pad lanes give NN
          v[k] = Abf[(size_t)sidx * 64 + lane];
        }
        float sx0 = 0.f, sx1 = 0.f, sy0 = 0.f, sy1 = 0.f;
#pragma unroll
        for (int k = 0; k < 16; k += 2) {
          sx0 += __uint_as_float(v[k] << 16);
          sy0 += __uint_as_float(v[k] & 0xffff0000u);
          sx1 += __uint_as_float(v[k + 1] << 16);
          sy1 += __uint_as_float(v[k + 1] & 0xffff0000u);
        }
        accx += sx0 + sx1;
        accy += sy0 + sy1;
      }
    }
    const float dv = dinv[n];
    float2 o;
    o.x = fmaf(accx, dv, bias2.x);
    o.y = fmaf(accy, dv, bias2.y);
    B2[(size_t)n * 64 + lane] = o;
    st1.x += o.x; st1.y += o.y;
    st2.x += o.x * o.x; st2.y += o.y * o.y;
  }

  // block-level BN-stat reduction (4 waves cover the same 128 features)
  __shared__ float2 red[256];
  red[t] = st1;
  __syncthreads();
  float2 t1;
  if (wave == 0) {
    t1.x = red[lane].x + red[lane + 64].x + red[lane + 128].x + red[lane + 192].x;
    t1.y = red[lane].y + red[lane + 64].y + red[lane + 128].y + red[lane + 192].y;
  }
  __syncthreads();
  red[t] = st2;
  __syncthreads();
  if (wave == 0) {
    float2 t2;
    t2.x = red[lane].x + red[lane + 64].x + red[lane + 128].x + red[lane + 192].x;
    t2.y = red[lane].y + red[lane + 64].y + red[lane + 128].y + red[lane + 192].y;
    atomicAddF(&stats[2 * lane + 0], t1.x);
    atomicAddF(&stats[2 * lane + 1], t1.y);
    atomicAddF(&stats[128 + 2 * lane + 0], t2.x);
    atomicAddF(&stats[128 + 2 * lane + 1], t2.y);
  }
}

// ---- BN finalize -> affine a,c ----
__global__ __launch_bounds__(128) void k_affine(const float* __restrict__ stats, const float* __restrict__ g,
                                                const float* __restrict__ be, float* __restrict__ af,
                                                float* __restrict__ cf) {
  int f = threadIdx.x;
  float mean = stats[f] * (1.f / NN);
  float var = stats[128 + f] * (1.f / NN) - mean * mean;
  var = fmaxf(var, 0.f);
  float inv = rsqrtf(var + EPSV);
  float a = g[f] * inv;
  af[f] = a;
  cf[f] = be[f] - mean * a;
}

// ---- GEMM: Abf[n,:] = bf16( dinv[n] * (relu(af*Bin[n,:]+cf) @ W) ) ----
#define GT_N 128
#define GT_KC 32
__global__ __launch_bounds__(256) void k_gemm(const float* __restrict__ Bin, const float* __restrict__ W,
                                              const float* __restrict__ af, const float* __restrict__ cf,
                                              const float* __restrict__ dinv, uint* __restrict__ Abf) {
  __shared__ float hs[GT_KC * 132];
  __shared__ float ws[GT_KC * 132];
  const int t = threadIdx.x;
  const int base = blockIdx.x * GT_N;
  const int tx = t & 15, ty = t >> 4;
  float acc[8][8];
#pragma unroll
  for (int a = 0; a < 8; a++)
#pragma unroll
    for (int b = 0; b < 8; b++) acc[a][b] = 0.f;

  for (int k0 = 0; k0 < HD; k0 += GT_KC) {
    __syncthreads();
    {
      const float4* W4 = (const float4*)(W + k0 * HD);
#pragma unroll
      for (int i = t; i < 1024; i += 256) {
        int row = i >> 5, c4 = i & 31;
        float4 v = W4[i];
        *(float4*)&ws[row * 132 + c4 * 4] = v;
      }
    }
    {
#pragma unroll
      for (int i = t; i < 1024; i += 256) {
        int node = i >> 3, c4 = i & 7;
        int n = base + node;
        float4 v = make_float4(0.f, 0.f, 0.f, 0.f);
        if (n < NN) v = *(const float4*)&Bin[(size_t)n * HD + k0 + c4 * 4];
        int kk = c4 * 4;
        float r0 = fmaxf(fmaf(af[k0 + kk + 0], v.x, cf[k0 + kk + 0]), 0.f);
        float r1 = fmaxf(fmaf(af[k0 + kk + 1], v.y, cf[k0 + kk + 1]), 0.f);
        float r2 = fmaxf(fmaf(af[k0 + kk + 2], v.z, cf[k0 + kk + 2]), 0.f);
        float r3 = fmaxf(fmaf(af[k0 + kk + 3], v.w, cf[k0 + kk + 3]), 0.f);
        hs[(kk + 0) * 132 + node] = r0;
        hs[(kk + 1) * 132 + node] = r1;
        hs[(kk + 2) * 132 + node] = r2;
        hs[(kk + 3) * 132 + node] = r3;
      }
    }
    __syncthreads();
#pragma unroll
    for (int k = 0; k < GT_KC; k++) {
      float4 h0 = *(float4*)&hs[k * 132 + ty * 8];
      float4 h1 = *(float4*)&hs[k * 132 + ty * 8 + 4];
      float4 w0 = *(float4*)&ws[k * 132 + tx * 8];
      float4 w1 = *(float4*)&ws[k * 132 + tx * 8 + 4];
      float hh[8] = {h0.x, h0.y, h0.z, h0.w, h1.x, h1.y, h1.z, h1.w};
      float wv[8] = {w0.x, w0.y, w0.z, w0.w, w1.x, w1.y, w1.z, w1.w};
#pragma unroll
      for (int a = 0; a < 8; a++)
#pragma unroll
        for (int b = 0; b < 8; b++) acc[a][b] = fmaf(hh[a], wv[b], acc[a][b]);
    }
  }
#pragma unroll
  for (int a = 0; a < 8; a++) {
    int n = base + ty * 8 + a;
    if (n < NN) {
      float s = dinv[n];
      uint4 o;
      o.x = pack2bf(acc[a][0] * s, acc[a][1] * s);
      o.y = pack2bf(acc[a][2] * s, acc[a][3] * s);
      o.z = pack2bf(acc[a][4] * s, acc[a][5] * s);
      o.w = pack2bf(acc[a][6] * s, acc[a][7] * s);
      *(uint4*)&Abf[(size_t)n * 64 + tx * 4] = o;
    }
  }
}

// ---- graph boundaries via binary search on sorted batch ----
__global__ __launch_bounds__(128) void k_bsearch(const int* __restrict__ batch, int* __restrict__ gstart) {
  int g = blockIdx.x * 128 + threadIdx.x;
  if (g > NG) return;
  if (g == NG) { gstart[NG] = NN; return; }
  int lo = 0, hi = NN;
  while (lo < hi) {
    int mid = (lo + hi) >> 1;
    if (batch[mid] < g) lo = mid + 1;
    else hi = mid;
  }
  gstart[g] = lo;
}

// ---- pool + FC ----
__global__ __launch_bounds__(128) void k_pool(const float* __restrict__ B, const float* __restrict__ af,
                                              const float* __restrict__ cf, const int* __restrict__ gstart,
                                              const float* __restrict__ fcW, const float* __restrict__ fcb,
                                              float* __restrict__ out) {
  int g = blockIdx.x, f = threadIdx.x;
  int gs = gstart[g], ge = gstart[g + 1];
  float a = af[f], c = cf[f];
  float a0 = 0.f, a1 = 0.f, a2 = 0.f, a3 = 0.f;
  int n = gs;
  for (; n + 4 <= ge; n += 4) {
    a0 += fmaxf(fmaf(a, B[(size_t)(n + 0) * HD + f], c), 0.f);
    a1 += fmaxf(fmaf(a, B[(size_t)(n + 1) * HD + f], c), 0.f);
    a2 += fmaxf(fmaf(a, B[(size_t)(n + 2) * HD + f], c), 0.f);
    a3 += fmaxf(fmaf(a, B[(size_t)(n + 3) * HD + f], c), 0.f);
  }
  for (; n < ge; n++) a0 += fmaxf(fmaf(a, B[(size_t)n * HD + f], c), 0.f);
  float acc = (a0 + a1) + (a2 + a3);
  float cntf = (float)(ge - gs);
  float pooled = acc / fmaxf(cntf, 1.f);
  __shared__ float lp[128];
  lp[f] = pooled;
  __syncthreads();
  if (f < 3) {
    float o = fcb[f];
    for (int k = 0; k < 128; k++) o += lp[k] * fcW[k * 3 + f];
    out[g * 3 + f] = o;
  }
}

extern "C" void kernel_launch(void* const* d_in, const int* in_sizes, int n_in,
                              void* d_out, int out_size, void* d_ws, size_t ws_size,
                              hipStream_t stream) {
  const float* x    = (const float*)d_in[0];
  const int* ei     = (const int*)d_in[1];
  const int* batch  = (const int*)d_in[2];
  const float* emb0 = (const float*)d_in[3];
  const float* emb1 = (const float*)d_in[4];
  const float* emb2 = (const float*)d_in[5];
  const float* emb5 = (const float*)d_in[6];
  const float* W1   = (const float*)d_in[7];
  const float* b1   = (const float*)d_in[8];
  const float* W2   = (const float*)d_in[9];
  const float* b2   = (const float*)d_in[10];
  const float* W3   = (const float*)d_in[11];
  const float* b3   = (const float*)d_in[12];
  const float* g1   = (const float*)d_in[13];
  const float* be1  = (const float*)d_in[14];
  const float* g2   = (const float*)d_in[15];
  const float* be2  = (const float*)d_in[16];
  const float* g3   = (const float*)d_in[17];
  const float* be3  = (const float*)d_in[18];
  const float* fcW  = (const float*)d_in[19];
  const float* fcb  = (const float*)d_in[20];
  float* out = (float*)d_out;

  const int* esrc = ei;
  const int* edst = ei + NE;

  char* p = (char*)d_ws;
  size_t o = 0;
  auto alloc = [&](size_t bytes) -> void* {
    o = (o + 255) & ~(size_t)255;
    void* r = p + o;
    o += bytes;
    return r;
  };
  int* cnt      = (int*)alloc(NN * 4);
  float* stats  = (float*)alloc(3 * 256 * 4);   // 3 layers x (sum,sumsq)
  size_t zbytes = o;                            // memset range covers cnt+stats
  int* off      = (int*)alloc((NN + 1) * 4);
  int* cursor   = (int*)alloc(NN * 4);
  int* csr      = (int*)alloc((size_t)(NE + NN + 64) * 4);
  float* dinv   = (float*)alloc(NN * 4);
  float* tabs   = (float*)alloc(470 * HD * 4);
  float* row0   = (float*)alloc(HD * 4);
  float* affine = (float*)alloc(3 * 256 * 4);   // 3 layers x (a,c)
  int* gstart   = (int*)alloc((NG + 1) * 4);
  uint* Abf     = (uint*)alloc((size_t)(NN + 1) * 64 * 4);   // bf16 rows, 256B each (+pad row)
  float* bufB   = (float*)alloc((size_t)NN * HD * 4);
  (void)ws_size; (void)n_in; (void)in_sizes; (void)out_size;

  hipMemsetAsync(d_ws, 0, zbytes, stream);

  k_count<<<(NE + 255) / 256, 256, 0, stream>>>(edst, cnt);
  k_scan<<<1, 1024, 0, stream>>>(cnt, off, cursor, dinv, csr, Abf + (size_t)NN * 64);
  k_fill<<<(NE + 255) / 256, 256, 0, stream>>>(esrc, edst, cursor, csr);
  k_tabs<<<471, 128, 0, stream>>>(emb0, emb1, emb2, emb5, W1, tabs, row0);
  k_bsearch<<<5, 128, 0, stream>>>(batch, gstart);
  k_embed<<<NN / 4, 256, 0, stream>>>(x, (const float2*)tabs, (const float2*)row0, dinv, Abf);

  const int nagg = NN / AGG_NPB;            // 3125, exact
  const int ngemm = (NN + GT_N - 1) / GT_N;

  // layer 1
  k_agg<<<nagg, 256, 0, stream>>>(Abf, off, csr, dinv, b1, bufB, stats + 0);
  k_affine<<<1, 128, 0, stream>>>(stats + 0, g1, be1, affine + 0, affine + 128);
  // layer 2
  k_gemm<<<ngemm, 256, 0, stream>>>(bufB, W2, affine + 0, affine + 128, dinv, Abf);
  k_agg<<<nagg, 256, 0, stream>>>(Abf, off, csr, dinv, b2, bufB, stats + 256);
  k_affine<<<1, 128, 0, stream>>>(stats + 256, g2, be2, affine + 256, affine + 384);
  // layer 3
  k_gemm<<<ngemm, 256, 0, stream>>>(bufB, W3, affine + 256, affine + 384, dinv, Abf);
  k_agg<<<nagg, 256, 0, stream>>>(Abf, off, csr, dinv, b3, bufB, stats + 512);
  k_affine<<<1, 128, 0, stream>>>(stats + 512, g3, be3, affine + 512, affine + 640);
  // pool + fc
  k_pool<<<NG, 128, 0, stream>>>(bufB, affine + 512, affine + 640, gstart, fcW, fcb, out);
}

// Round 7
// 536.856 us; speedup vs baseline: 1.4348x; 1.3875x over previous
//
#include <hip/hip_runtime.h>

#define NN 50000
#define NE 600000
#define NG 512
#define HD 128
#define EPSV 1e-5f

typedef unsigned int uint;

__device__ inline void atomicAddF(float* p, float v) {
  __hip_atomic_fetch_add(p, v, __ATOMIC_RELAXED, __HIP_MEMORY_SCOPE_AGENT);
}

__device__ inline uint bf16rne(float f) {
  uint u = __float_as_uint(f);
  return (u + 0x7fffu + ((u >> 16) & 1u)) >> 16;
}
__device__ inline uint pack2bf(float a, float b) {
  return bf16rne(a) | (bf16rne(b) << 16);
}
__device__ inline float lo16f(uint u) { return __uint_as_float(u << 16); }
__device__ inline float hi16f(uint u) { return __uint_as_float(u & 0xffff0000u); }

// ---- CSR build (self-edge first in each node's list) ----
__global__ __launch_bounds__(256) void k_count(const int* __restrict__ dst, int* __restrict__ cnt) {
  int e = blockIdx.x * 256 + threadIdx.x;
  if (e < NE) atomicAdd(&cnt[dst[e]], 1);
}

// 4 elements per thread, 13 iterations; also zeroes Abf's pad row NN.
__global__ __launch_bounds__(1024) void k_scan(const int* __restrict__ cnt, int* __restrict__ off,
                                               int* __restrict__ cursor, float* __restrict__ dinv,
                                               int* __restrict__ csr, uint* __restrict__ zrow) {
  __shared__ int part[16];
  __shared__ int partscan[16];
  int t = threadIdx.x;
  int lane = t & 63, w = t >> 6;
  if (t < 64) zrow[t] = 0u;   // zero pad row (bf16 row = 64 uints)
  int carry = 0;
  for (int base = 0; base < NN; base += 4096) {
    int i0 = base + 4 * t;
    int c[4], v[4];
#pragma unroll
    for (int j = 0; j < 4; j++) {
      int idx = i0 + j;
      c[j] = (idx < NN) ? cnt[idx] : 0;
      v[j] = (idx < NN) ? (c[j] + 1) : 0;
    }
    int tsum = (v[0] + v[1]) + (v[2] + v[3]);
    int val = tsum;
#pragma unroll
    for (int s = 1; s < 64; s <<= 1) {
      int u = __shfl_up(val, s);
      if (lane >= s) val += u;
    }
    if (lane == 63) part[w] = val;
    __syncthreads();
    if (t == 0) {
      int acc = 0;
#pragma unroll
      for (int i = 0; i < 16; i++) { acc += part[i]; partscan[i] = acc; }
    }
    __syncthreads();
    int waveoff = (w > 0) ? partscan[w - 1] : 0;
    int run = val - tsum + waveoff + carry;
#pragma unroll
    for (int j = 0; j < 4; j++) {
      int idx = i0 + j;
      if (idx < NN) {
        off[idx] = run;
        cursor[idx] = run + 1;
        csr[run] = idx;                        // self-edge
        dinv[idx] = rsqrtf((float)c[j] + 1.0f);
        run += v[j];
      }
    }
    carry += partscan[15];
    __syncthreads();
  }
  if (t == 0) off[NN] = carry;
}

__global__ __launch_bounds__(256) void k_fill(const int* __restrict__ src, const int* __restrict__ dst,
                                              int* __restrict__ cursor, int* __restrict__ csr) {
  int e = blockIdx.x * 256 + threadIdx.x;
  if (e < NE) {
    int p = atomicAdd(&cursor[dst[e]], 1);
    csr[p] = src[e];
  }
}

// ---- fused embedding tables: T = emb @ W1[rows] ----
__global__ __launch_bounds__(128) void k_tabs(const float* __restrict__ emb0, const float* __restrict__ emb1,
                                              const float* __restrict__ emb2, const float* __restrict__ emb5,
                                              const float* __restrict__ W1, float* __restrict__ tabs,
                                              float* __restrict__ row0) {
  int r = blockIdx.x, f = threadIdx.x;
  if (r == 470) { row0[f] = W1[f]; return; }
  const float* e;
  int wbase;
  if (r < 96)      { e = emb0 + r * 32;        wbase = 1;  }
  else if (r < 192){ e = emb1 + (r - 96) * 32; wbase = 33; }
  else if (r < 288){ e = emb2 + (r - 192) * 32; wbase = 65; }
  else             { e = emb5 + (r - 288) * 32; wbase = 97; }
  float acc = 0.f;
#pragma unroll 8
  for (int k = 0; k < 32; k++) acc += e[k] * W1[(wbase + k) * HD + f];
  tabs[r * HD + f] = acc;
}

// ---- layer-1: embed + axpy + pre-scale by dinv; packed bf16 output ----
__global__ __launch_bounds__(256) void k_embed(const float* __restrict__ x, const float2* __restrict__ tabs2,
                                               const float2* __restrict__ row02, const float* __restrict__ dinv,
                                               uint* __restrict__ Abf) {
  int n = blockIdx.x * 4 + (threadIdx.x >> 6);   // grid exact: 12500*4 = NN
  int lane = threadIdx.x & 63;
  float poss = x[n * 5 + 0];
  int i0 = (int)x[n * 5 + 1];
  int i1 = (int)x[n * 5 + 2];
  int i2 = (int)x[n * 5 + 3];
  int i5 = (int)x[n * 5 + 4];
  float2 r0 = row02[lane];
  float2 t0 = tabs2[(size_t)i0 * 64 + lane];
  float2 t1 = tabs2[(size_t)(96 + i1) * 64 + lane];
  float2 t2 = tabs2[(size_t)(192 + i2) * 64 + lane];
  float2 t5 = tabs2[(size_t)(288 + i5) * 64 + lane];
  float hx = poss * r0.x + t0.x + t1.x + t2.x + t5.x;
  float hy = poss * r0.y + t0.y + t1.y + t2.y + t5.y;
  float dv = dinv[n];
  Abf[(size_t)n * 64 + lane] = pack2bf(hx * dv, hy * dv);
}

// ---- aggregation v7: 4 neighbor rows per gather instruction.
// Row = 256B bf16 = 16 lanes x uint4. Lane-group grp=lane>>4 takes neighbor
// 4j+grp (index via ds_bpermute from preloaded ev); cross-group combine by
// shfl_xor butterfly. CSR list per node = [self, neighbors...].
// B[n] = dinv[n]*sum(Abf rows) + bias. Pads read zeroed row NN.
#define AGG_NPW 4
#define AGG_NPB (4 * AGG_NPW)
__global__ __launch_bounds__(256) void k_agg(const uint* __restrict__ Abf, const int* __restrict__ off,
                                             const int* __restrict__ csr, const float* __restrict__ dinv,
                                             const float* __restrict__ bias, float* __restrict__ B,
                                             float* __restrict__ stats) {
  const int t = threadIdx.x, lane = t & 63, wave = t >> 6;
  const int grp = lane >> 4, p = lane & 15;
  __shared__ float sredb[16][17];   // [p][8 sums + 8 sumsqs], padded
  for (int q = t; q < 16 * 17; q += 256) ((float*)sredb)[q] = 0.f;
  __syncthreads();

  const float4 bias03 = ((const float4*)bias)[p * 2];
  const float4 bias47 = ((const float4*)bias)[p * 2 + 1];

  const int n0 = blockIdx.x * AGG_NPB + wave * AGG_NPW;   // grid exact
  int sv = 0;
  { int q = n0 + lane; if (lane <= AGG_NPW) sv = off[q]; }

  // preload all 4 nodes' first-64 edge indices (4 independent loads in flight)
  int ev[AGG_NPW];
#pragma unroll
  for (int i = 0; i < AGG_NPW; i++) {
    int ks = __shfl(sv, i), ke = __shfl(sv, i + 1);
    int rem = ke - ks;
    ev[i] = (lane < rem) ? csr[ks + lane] : NN;
  }

#pragma unroll 1
  for (int i = 0; i < AGG_NPW; i++) {
    const int ks = __shfl(sv, i);
    const int ke = __shfl(sv, i + 1);
    const int deg = ke - ks;
    float acc[8] = {0.f, 0.f, 0.f, 0.f, 0.f, 0.f, 0.f, 0.f};
    int evi = ev[i];
#pragma unroll 1
    for (int c0 = 0; c0 < deg; c0 += 64) {
      if (c0 > 0) {                     // rare: deg > 64
        int rem = deg - c0;
        evi = (lane < rem) ? csr[ks + c0 + lane] : NN;
      }
      const int lim = min(deg - c0, 64);
#pragma unroll 1
      for (int j0 = 0; j0 < lim; j0 += 16) {
        uint4 v[4];
#pragma unroll
        for (int m = 0; m < 4; m++) {
          int nb = __shfl(evi, j0 + 4 * m + grp);  // pad slots give NN
          v[m] = *(const uint4*)((const char*)Abf + (((size_t)nb) << 8) + (p << 4));
        }
#pragma unroll
        for (int m = 0; m < 4; m++) {
          acc[0] += lo16f(v[m].x); acc[1] += hi16f(v[m].x);
          acc[2] += lo16f(v[m].y); acc[3] += hi16f(v[m].y);
          acc[4] += lo16f(v[m].z); acc[5] += hi16f(v[m].z);
          acc[6] += lo16f(v[m].w); acc[7] += hi16f(v[m].w);
        }
      }
    }
    // combine the 4 lane-groups (each summed a disjoint neighbor subset)
#pragma unroll
    for (int q = 0; q < 8; q++) {
      acc[q] += __shfl_xor(acc[q], 16);
      acc[q] += __shfl_xor(acc[q], 32);
    }
    const float dv = dinv[n0 + i];
    float o[8];
    o[0] = fmaf(acc[0], dv, bias03.x); o[1] = fmaf(acc[1], dv, bias03.y);
    o[2] = fmaf(acc[2], dv, bias03.z); o[3] = fmaf(acc[3], dv, bias03.w);
    o[4] = fmaf(acc[4], dv, bias47.x); o[5] = fmaf(acc[5], dv, bias47.y);
    o[6] = fmaf(acc[6], dv, bias47.z); o[7] = fmaf(acc[7], dv, bias47.w);
    if (grp == 0) {
      float4 w0 = make_float4(o[0], o[1], o[2], o[3]);
      float4 w1 = make_float4(o[4], o[5], o[6], o[7]);
      *(float4*)&B[(size_t)(n0 + i) * HD + p * 8] = w0;
      *(float4*)&B[(size_t)(n0 + i) * HD + p * 8 + 4] = w1;
#pragma unroll
      for (int q = 0; q < 8; q++) {
        atomicAdd(&sredb[p][q], o[q]);
        atomicAdd(&sredb[p][8 + q], o[q] * o[q]);
      }
    }
  }
  __syncthreads();
  {
    int pp = t >> 4, ii = t & 15;
    float v = sredb[pp][ii];
    atomicAddF(&stats[(ii < 8 ? 0 : 128) + pp * 8 + (ii & 7)], v);
  }
}

// ---- BN finalize -> affine a,c ----
__global__ __launch_bounds__(128) void k_affine(const float* __restrict__ stats, const float* __restrict__ g,
                                                const float* __restrict__ be, float* __restrict__ af,
                                                float* __restrict__ cf) {
  int f = threadIdx.x;
  float mean = stats[f] * (1.f / NN);
  float var = stats[128 + f] * (1.f / NN) - mean * mean;
  var = fmaxf(var, 0.f);
  float inv = rsqrtf(var + EPSV);
  float a = g[f] * inv;
  af[f] = a;
  cf[f] = be[f] - mean * a;
}

// ---- GEMM: Abf[n,:] = bf16( dinv[n] * (relu(af*Bin[n,:]+cf) @ W) ) ----
#define GT_N 128
#define GT_KC 32
__global__ __launch_bounds__(256) void k_gemm(const float* __restrict__ Bin, const float* __restrict__ W,
                                              const float* __restrict__ af, const float* __restrict__ cf,
                                              const float* __restrict__ dinv, uint* __restrict__ Abf) {
  __shared__ float hs[GT_KC * 132];
  __shared__ float ws[GT_KC * 132];
  const int t = threadIdx.x;
  const int base = blockIdx.x * GT_N;
  const int tx = t & 15, ty = t >> 4;
  float acc[8][8];
#pragma unroll
  for (int a = 0; a < 8; a++)
#pragma unroll
    for (int b = 0; b < 8; b++) acc[a][b] = 0.f;

  for (int k0 = 0; k0 < HD; k0 += GT_KC) {
    __syncthreads();
    {
      const float4* W4 = (const float4*)(W + k0 * HD);
#pragma unroll
      for (int i = t; i < 1024; i += 256) {
        int row = i >> 5, c4 = i & 31;
        float4 v = W4[i];
        *(float4*)&ws[row * 132 + c4 * 4] = v;
      }
    }
    {
#pragma unroll
      for (int i = t; i < 1024; i += 256) {
        int node = i >> 3, c4 = i & 7;
        int n = base + node;
        float4 v = make_float4(0.f, 0.f, 0.f, 0.f);
        if (n < NN) v = *(const float4*)&Bin[(size_t)n * HD + k0 + c4 * 4];
        int kk = c4 * 4;
        float r0 = fmaxf(fmaf(af[k0 + kk + 0], v.x, cf[k0 + kk + 0]), 0.f);
        float r1 = fmaxf(fmaf(af[k0 + kk + 1], v.y, cf[k0 + kk + 1]), 0.f);
        float r2 = fmaxf(fmaf(af[k0 + kk + 2], v.z, cf[k0 + kk + 2]), 0.f);
        float r3 = fmaxf(fmaf(af[k0 + kk + 3], v.w, cf[k0 + kk + 3]), 0.f);
        hs[(kk + 0) * 132 + node] = r0;
        hs[(kk + 1) * 132 + node] = r1;
        hs[(kk + 2) * 132 + node] = r2;
        hs[(kk + 3) * 132 + node] = r3;
      }
    }
    __syncthreads();
#pragma unroll
    for (int k = 0; k < GT_KC; k++) {
      float4 h0 = *(float4*)&hs[k * 132 + ty * 8];
      float4 h1 = *(float4*)&hs[k * 132 + ty * 8 + 4];
      float4 w0 = *(float4*)&ws[k * 132 + tx * 8];
      float4 w1 = *(float4*)&ws[k * 132 + tx * 8 + 4];
      float hh[8] = {h0.x, h0.y, h0.z, h0.w, h1.x, h1.y, h1.z, h1.w};
      float wv[8] = {w0.x, w0.y, w0.z, w0.w, w1.x, w1.y, w1.z, w1.w};
#pragma unroll
      for (int a = 0; a < 8; a++)
#pragma unroll
        for (int b = 0; b < 8; b++) acc[a][b] = fmaf(hh[a], wv[b], acc[a][b]);
    }
  }
#pragma unroll
  for (int a = 0; a < 8; a++) {
    int n = base + ty * 8 + a;
    if (n < NN) {
      float s = dinv[n];
      uint4 o;
      o.x = pack2bf(acc[a][0] * s, acc[a][1] * s);
      o.y = pack2bf(acc[a][2] * s, acc[a][3] * s);
      o.z = pack2bf(acc[a][4] * s, acc[a][5] * s);
      o.w = pack2bf(acc[a][6] * s, acc[a][7] * s);
      *(uint4*)&Abf[(size_t)n * 64 + tx * 4] = o;
    }
  }
}

// ---- graph boundaries via binary search on sorted batch ----
__global__ __launch_bounds__(128) void k_bsearch(const int* __restrict__ batch, int* __restrict__ gstart) {
  int g = blockIdx.x * 128 + threadIdx.x;
  if (g > NG) return;
  if (g == NG) { gstart[NG] = NN; return; }
  int lo = 0, hi = NN;
  while (lo < hi) {
    int mid = (lo + hi) >> 1;
    if (batch[mid] < g) lo = mid + 1;
    else hi = mid;
  }
  gstart[g] = lo;
}

// ---- pool + FC ----
__global__ __launch_bounds__(128) void k_pool(const float* __restrict__ B, const float* __restrict__ af,
                                              const float* __restrict__ cf, const int* __restrict__ gstart,
                                              const float* __restrict__ fcW, const float* __restrict__ fcb,
                                              float* __restrict__ out) {
  int g = blockIdx.x, f = threadIdx.x;
  int gs = gstart[g], ge = gstart[g + 1];
  float a = af[f], c = cf[f];
  float a0 = 0.f, a1 = 0.f, a2 = 0.f, a3 = 0.f;
  int n = gs;
  for (; n + 4 <= ge; n += 4) {
    a0 += fmaxf(fmaf(a, B[(size_t)(n + 0) * HD + f], c), 0.f);
    a1 += fmaxf(fmaf(a, B[(size_t)(n + 1) * HD + f], c), 0.f);
    a2 += fmaxf(fmaf(a, B[(size_t)(n + 2) * HD + f], c), 0.f);
    a3 += fmaxf(fmaf(a, B[(size_t)(n + 3) * HD + f], c), 0.f);
  }
  for (; n < ge; n++) a0 += fmaxf(fmaf(a, B[(size_t)n * HD + f], c), 0.f);
  float acc = (a0 + a1) + (a2 + a3);
  float cntf = (float)(ge - gs);
  float pooled = acc / fmaxf(cntf, 1.f);
  __shared__ float lp[128];
  lp[f] = pooled;
  __syncthreads();
  if (f < 3) {
    float o = fcb[f];
    for (int k = 0; k < 128; k++) o += lp[k] * fcW[k * 3 + f];
    out[g * 3 + f] = o;
  }
}

extern "C" void kernel_launch(void* const* d_in, const int* in_sizes, int n_in,
                              void* d_out, int out_size, void* d_ws, size_t ws_size,
                              hipStream_t stream) {
  const float* x    = (const float*)d_in[0];
  const int* ei     = (const int*)d_in[1];
  const int* batch  = (const int*)d_in[2];
  const float* emb0 = (const float*)d_in[3];
  const float* emb1 = (const float*)d_in[4];
  const float* emb2 = (const float*)d_in[5];
  const float* emb5 = (const float*)d_in[6];
  const float* W1   = (const float*)d_in[7];
  const float* b1   = (const float*)d_in[8];
  const float* W2   = (const float*)d_in[9];
  const float* b2   = (const float*)d_in[10];
  const float* W3   = (const float*)d_in[11];
  const float* b3   = (const float*)d_in[12];
  const float* g1   = (const float*)d_in[13];
  const float* be1  = (const float*)d_in[14];
  const float* g2   = (const float*)d_in[15];
  const float* be2  = (const float*)d_in[16];
  const float* g3   = (const float*)d_in[17];
  const float* be3  = (const float*)d_in[18];
  const float* fcW  = (const float*)d_in[19];
  const float* fcb  = (const float*)d_in[20];
  float* out = (float*)d_out;

  const int* esrc = ei;
  const int* edst = ei + NE;

  char* p = (char*)d_ws;
  size_t o = 0;
  auto alloc = [&](size_t bytes) -> void* {
    o = (o + 255) & ~(size_t)255;
    void* r = p + o;
    o += bytes;
    return r;
  };
  int* cnt      = (int*)alloc(NN * 4);
  float* stats  = (float*)alloc(3 * 256 * 4);   // 3 layers x (sum,sumsq)
  size_t zbytes = o;                            // memset range covers cnt+stats
  int* off      = (int*)alloc((NN + 1) * 4);
  int* cursor   = (int*)alloc(NN * 4);
  int* csr      = (int*)alloc((size_t)(NE + NN + 64) * 4);
  float* dinv   = (float*)alloc(NN * 4);
  float* tabs   = (float*)alloc(470 * HD * 4);
  float* row0   = (float*)alloc(HD * 4);
  float* affine = (float*)alloc(3 * 256 * 4);   // 3 layers x (a,c)
  int* gstart   = (int*)alloc((NG + 1) * 4);
  uint* Abf     = (uint*)alloc((size_t)(NN + 1) * 64 * 4);   // bf16 rows, 256B each (+pad row)
  float* bufB   = (float*)alloc((size_t)NN * HD * 4);
  (void)ws_size; (void)n_in; (void)in_sizes; (void)out_size;

  hipMemsetAsync(d_ws, 0, zbytes, stream);

  k_count<<<(NE + 255) / 256, 256, 0, stream>>>(edst, cnt);
  k_scan<<<1, 1024, 0, stream>>>(cnt, off, cursor, dinv, csr, Abf + (size_t)NN * 64);
  k_fill<<<(NE + 255) / 256, 256, 0, stream>>>(esrc, edst, cursor, csr);
  k_tabs<<<471, 128, 0, stream>>>(emb0, emb1, emb2, emb5, W1, tabs, row0);
  k_bsearch<<<5, 128, 0, stream>>>(batch, gstart);
  k_embed<<<NN / 4, 256, 0, stream>>>(x, (const float2*)tabs, (const float2*)row0, dinv, Abf);

  const int nagg = NN / AGG_NPB;            // 3125, exact
  const int ngemm = (NN + GT_N - 1) / GT_N;

  // layer 1
  k_agg<<<nagg, 256, 0, stream>>>(Abf, off, csr, dinv, b1, bufB, stats + 0);
  k_affine<<<1, 128, 0, stream>>>(stats + 0, g1, be1, affine + 0, affine + 128);
  // layer 2
  k_gemm<<<ngemm, 256, 0, stream>>>(bufB, W2, affine + 0, affine + 128, dinv, Abf);
  k_agg<<<nagg, 256, 0, stream>>>(Abf, off, csr, dinv, b2, bufB, stats + 256);
  k_affine<<<1, 128, 0, stream>>>(stats + 256, g2, be2, affine + 256, affine + 384);
  // layer 3
  k_gemm<<<ngemm, 256, 0, stream>>>(bufB, W3, affine + 256, affine + 384, dinv, Abf);
  k_agg<<<nagg, 256, 0, stream>>>(Abf, off, csr, dinv, b3, bufB, stats + 512);
  k_affine<<<1, 128, 0, stream>>>(stats + 512, g3, be3, affine + 512, affine + 640);
  // pool + fc
  k_pool<<<NG, 128, 0, stream>>>(bufB, affine + 512, affine + 640, gstart, fcW, fcb, out);
}